// Round 4
// baseline (453.456 us; speedup 1.0000x reference)
//
#include <hip/hip_runtime.h>
#include <float.h>

#define DECAY 0.99f
#define EPS 1e-5f
#define NROWS 65536
#define DIM 256
#define NEMB 1024
#define CH 64            // rows per sub-chunk in segmented reduction
#define MAXSUB 2048      // NROWS/CH + NEMB upper bound on total sub-chunks

typedef _Float16 f16;
typedef _Float16 half8 __attribute__((ext_vector_type(8)));
typedef float f32x4 __attribute__((ext_vector_type(4)));

// ---------- K0a: ||e_k||^2 per code + zero counts ----------
__global__ __launch_bounds__(256) void k_enorm(const float* __restrict__ embed,
                                               float* __restrict__ enorm2,
                                               int* __restrict__ counts) {
    int kk = threadIdx.x & 63;
    int dg = threadIdx.x >> 6;              // 0..3
    int k  = blockIdx.x * 64 + kk;          // 16 blocks * 64 = 1024 codes
    float s = 0.f;
    for (int d = dg; d < DIM; d += 4) {
        float v = embed[(size_t)d * NEMB + k];
        s = fmaf(v, v, s);
    }
    __shared__ float red[4][64];
    red[dg][kk] = s;
    __syncthreads();
    if (dg == 0) enorm2[k] = red[0][kk] + red[1][kk] + red[2][kk] + red[3][kk];
    int gt = blockIdx.x * 256 + threadIdx.x;
    if (gt < NEMB) counts[gt] = 0;
}

// ---------- K0b: transpose embed [256][1024] -> embedT [1024][256] (for k_quant) ----------
__global__ __launch_bounds__(256) void k_transpose(const float* __restrict__ embed,
                                                   float* __restrict__ embedT) {
    __shared__ float tile[32][33];
    int k0 = blockIdx.x * 32, d0 = blockIdx.y * 32;
    int tx = threadIdx.x, ty = threadIdx.y;  // 32 x 8
#pragma unroll
    for (int i = 0; i < 4; i++)
        tile[ty + 8 * i][tx] = embed[(size_t)(d0 + ty + 8 * i) * NEMB + k0 + tx];
    __syncthreads();
#pragma unroll
    for (int i = 0; i < 4; i++)
        embedT[(size_t)(k0 + ty + 8 * i) * DIM + d0 + tx] = tile[tx][ty + 8 * i];
}

// ---------- K0c: embed fp32 [256][1024] -> ehlT f16 [1024][512] ([c][0:256]=hi, [c][256:512]=lo) ----------
__global__ __launch_bounds__(256) void k_esplit(const float* __restrict__ embed,
                                                f16* __restrict__ ehlT) {
    __shared__ float tile[32][33];           // [d-local][c-local]
    int c0 = blockIdx.x * 32, d0 = blockIdx.y * 32;
    int tx = threadIdx.x, ty = threadIdx.y;  // 32 x 8
#pragma unroll
    for (int i = 0; i < 4; i++)
        tile[ty + 8 * i][tx] = embed[(size_t)(d0 + ty + 8 * i) * NEMB + c0 + tx];
    __syncthreads();
#pragma unroll
    for (int i = 0; i < 4; i++) {
        int c = c0 + ty + 8 * i;
        int d = d0 + tx;
        float v = tile[tx][ty + 8 * i];
        f16 h = (f16)v;
        f16 l = (f16)(v - (float)h);
        ehlT[(size_t)c * 512 + d]       = h;
        ehlT[(size_t)c * 512 + 256 + d] = l;
    }
}

// ---------- K1: MFMA GEMM-argmin, A fully LDS-resident, input read ONCE ----------
// Block: 128 rows x 1024 cols (16 slabs of 64). A = [128 rows][512 f16] = 128KB LDS.
// B: double-buffered 8KB tiles (64 cols x 64 k), reg-staged async from ehlT (L2-hot).
#define LDS_A  0         // 128KB, row*1024 + ((slot*16) ^ ((row&7)<<4))
#define LDS_B0 131072    // 8KB
#define LDS_B1 139264    // 8KB
#define LDS_E  147456    // 4KB Es
#define LDS_SZ 151552

__global__ __launch_bounds__(256, 1) void k_argmin_mfma(const float* __restrict__ input,
                                                        const f16* __restrict__ ehlT,
                                                        const float* __restrict__ enorm2,
                                                        int* __restrict__ ind,
                                                        float* __restrict__ out_ind) {
    __shared__ char lds[LDS_SZ];
    float* Es = (float*)(lds + LDS_E);
    const int tid  = threadIdx.x;
    const int lane = tid & 63;
    const int w    = tid >> 6;        // wave 0..3
    const int wr   = w >> 1;          // row half (0/1): rows wr*64..+64
    const int wc   = w & 1;           // col half (0/1): cols wc*32..+32 within 64-slab
    const int rb   = blockIdx.x * 128;
    const int l15  = lane & 15;
    const int lkh  = lane >> 4;       // 0..3

    for (int j = tid; j < NEMB; j += 256) Es[j] = enorm2[j];

    // ---- stage A once: 128 rows x 256 d fp32 -> hi/lo f16, swizzled LDS ----
#pragma unroll
    for (int it8 = 0; it8 < 8; it8++) {
        int task = tid + 256 * it8;          // 0..2047
        int row = task >> 4, ch = task & 15; // ch = 16-d chunk
        const float4* g = (const float4*)(input + (size_t)(rb + row) * DIM + ch * 16);
        float fv[16];
        *(float4*)(fv + 0)  = g[0];
        *(float4*)(fv + 4)  = g[1];
        *(float4*)(fv + 8)  = g[2];
        *(float4*)(fv + 12) = g[3];
        half8 hh[2], llv[2];
#pragma unroll
        for (int u = 0; u < 2; u++)
#pragma unroll
            for (int e = 0; e < 8; e++) {
                float x = fv[u * 8 + e];
                f16 h = (f16)x;
                hh[u][e]  = h;
                llv[u][e] = (f16)(x - (float)h);
            }
        int rbase = row * 1024;
        int sw = (row & 7) << 4;
        *(half8*)(lds + LDS_A + rbase + (((ch * 2    ) * 16) ^ sw)) = hh[0];
        *(half8*)(lds + LDS_A + rbase + (((ch * 2 + 1) * 16) ^ sw)) = hh[1];
        *(half8*)(lds + LDS_A + rbase + (((32 + ch * 2) * 16) ^ sw)) = llv[0];
        *(half8*)(lds + LDS_A + rbase + (((33 + ch * 2) * 16) ^ sw)) = llv[1];
    }

    // ---- B prologue: tile it=0 (ct=0, kt=0 -> chunk q=0, cb=0) ----
    {
        int n0 = tid, col0 = n0 >> 3, m0 = n0 & 7;
        float4 pb0 = *(const float4*)(ehlT + (size_t)col0 * 512 + m0 * 8);
        int n1 = tid + 256, col1 = n1 >> 3, m1 = n1 & 7;
        float4 pb1 = *(const float4*)(ehlT + (size_t)col1 * 512 + m1 * 8);
        *(half8*)(lds + LDS_B0 + col0 * 128 + ((m0 * 16) ^ ((col0 & 7) << 4))) = *(half8*)&pb0;
        *(half8*)(lds + LDS_B0 + col1 * 128 + ((m1 * 16) ^ ((col1 & 7) << 4))) = *(half8*)&pb1;
    }
    __syncthreads();   // A + B0 visible

    float bv[16];
    int   bi[16];
#pragma unroll
    for (int q = 0; q < 16; q++) { bv[q] = FLT_MAX; bi[q] = 0x7fffffff; }

    int p = 0;
    for (int ct = 0; ct < 16; ct++) {
        const int cb = ct * 64;
        f32x4 acc[4][2];
#pragma unroll
        for (int fr = 0; fr < 4; fr++)
#pragma unroll
            for (int fc = 0; fc < 2; fc++) acc[fr][fc] = (f32x4){0.f, 0.f, 0.f, 0.f};

        for (int kt = 0; kt < 12; kt++) {
            const int it = ct * 12 + kt;
            const bool hn = (it < 191);
            // ---- prefetch next B tile into regs (T14 issue-early) ----
            float4 nb0, nb1;
            int wcol0 = 0, wm0 = 0, wcol1 = 0, wm1 = 0;
            if (hn) {
                int itn = it + 1;
                int ct2 = itn / 12;
                int kt2 = itn - ct2 * 12;
                int cb2 = ct2 * 64;
                int ksec2 = kt2 >> 2, kq2 = kt2 & 3;
                int q2 = ((ksec2 == 2) ? 4 : 0) + kq2;      // ehlT 64-f16 chunk
                int n0 = tid; wcol0 = n0 >> 3; wm0 = n0 & 7;
                nb0 = *(const float4*)(ehlT + (size_t)(cb2 + wcol0) * 512 + q2 * 64 + wm0 * 8);
                int n1 = tid + 256; wcol1 = n1 >> 3; wm1 = n1 & 7;
                nb1 = *(const float4*)(ehlT + (size_t)(cb2 + wcol1) * 512 + q2 * 64 + wm1 * 8);
            }
            // ---- MFMA on current tile ----
            const int ksec = kt >> 2, kq = kt & 3;
            const int aslotb = ((ksec == 1) ? 32 : 0) + kq * 8;   // A slot base (hi/lo quarter)
            const char* Bb = lds + (p ? LDS_B1 : LDS_B0);
#pragma unroll
            for (int kk = 0; kk < 2; kk++) {
                const int j = kk * 4 + lkh;                       // 16B k-slot within tile
                half8 af[4], bf[2];
#pragma unroll
                for (int f = 0; f < 4; f++) {
                    int row = wr * 64 + f * 16 + l15;
                    af[f] = *(const half8*)(lds + LDS_A + row * 1024 +
                                            (((aslotb + j) * 16) ^ ((row & 7) << 4)));
                }
#pragma unroll
                for (int f = 0; f < 2; f++) {
                    int col = wc * 32 + f * 16 + l15;
                    bf[f] = *(const half8*)(Bb + col * 128 + ((j * 16) ^ ((col & 7) << 4)));
                }
#pragma unroll
                for (int fr = 0; fr < 4; fr++)
#pragma unroll
                    for (int fc = 0; fc < 2; fc++)
                        acc[fr][fc] = __builtin_amdgcn_mfma_f32_16x16x32_f16(
                            af[fr], bf[fc], acc[fr][fc], 0, 0, 0);
            }
            // ---- write prefetched tile to the other buffer ----
            if (hn) {
                char* Bn = lds + (p ? LDS_B0 : LDS_B1);
                *(half8*)(Bn + wcol0 * 128 + ((wm0 * 16) ^ ((wcol0 & 7) << 4))) = *(half8*)&nb0;
                *(half8*)(Bn + wcol1 * 128 + ((wm1 * 16) ^ ((wcol1 & 7) << 4))) = *(half8*)&nb1;
            }
            // ---- slab epilogue: running argmin ----
            if (kt == 11) {
#pragma unroll
                for (int fc = 0; fc < 2; fc++) {
                    int col = cb + wc * 32 + fc * 16 + l15;
                    float e2 = Es[col];
#pragma unroll
                    for (int fr = 0; fr < 4; fr++)
#pragma unroll
                        for (int r = 0; r < 4; r++) {
                            float s = fmaf(-2.f, acc[fr][fc][r], e2);
                            int q = fr * 4 + r;
                            if (s < bv[q]) { bv[q] = s; bi[q] = col; }
                        }
                }
            }
            __syncthreads();
            p ^= 1;
        }
    }

    // ---- cross-lane reduce: min over the 16 col-lanes ----
#pragma unroll
    for (int q = 0; q < 16; q++) {
        float v = bv[q]; int i = bi[q];
#pragma unroll
        for (int m = 1; m <= 8; m <<= 1) {
            float ov = __shfl_xor(v, m, 64);
            int   oi = __shfl_xor(i, m, 64);
            if (ov < v || (ov == v && oi < i)) { v = ov; i = oi; }
        }
        bv[q] = v; bi[q] = i;
    }
    // overlay PV/PI on B buffers (all MFMA reads done: last barrier passed)
    float* PV = (float*)(lds + LDS_B0);
    int*   PI = (int*)(lds + LDS_B0 + 1024);
    if (l15 == 0) {
#pragma unroll
        for (int fr = 0; fr < 4; fr++)
#pragma unroll
            for (int r = 0; r < 4; r++) {
                int rrow = wr * 64 + fr * 16 + lkh * 4 + r;
                PV[rrow * 2 + wc] = bv[fr * 4 + r];
                PI[rrow * 2 + wc] = bi[fr * 4 + r];
            }
    }
    __syncthreads();
    if (tid < 128) {
        float v0 = PV[tid * 2], v1 = PV[tid * 2 + 1];
        int   i0 = PI[tid * 2], i1 = PI[tid * 2 + 1];
        int best;
        if (v1 < v0) best = i1;
        else if (v0 < v1) best = i0;
        else best = min(i0, i1);
        ind[rb + tid] = best;
        out_ind[rb + tid] = (float)best;
    }
}

// ---------- K2: quantize_st output + per-block diff partials ----------
__global__ __launch_bounds__(256) void k_quant(const float* __restrict__ input,
                                               const float* __restrict__ embedT,
                                               const int* __restrict__ ind,
                                               float* __restrict__ out_q,
                                               float* __restrict__ partials) {
    const int tid = threadIdx.x;
    const unsigned gid = blockIdx.x * 256 + tid;
    float s = 0.f;
#pragma unroll
    for (int j = 0; j < 8; j++) {
        size_t i4 = (size_t)gid + (size_t)j * 524288u;   // 4194304 float4 total
        int row = (int)(i4 >> 6);
        int d4  = (int)(i4 & 63);
        float4 iv = *reinterpret_cast<const float4*>(input + i4 * 4);
        int k = ind[row];
        float4 qv = *reinterpret_cast<const float4*>(embedT + (size_t)k * DIM + d4 * 4);
        float dx = qv.x - iv.x, dy = qv.y - iv.y, dz = qv.z - iv.z, dw = qv.w - iv.w;
        float4 ov;
        ov.x = iv.x + dx; ov.y = iv.y + dy; ov.z = iv.z + dz; ov.w = iv.w + dw;
        *reinterpret_cast<float4*>(out_q + i4 * 4) = ov;
        s += dx * dx + dy * dy + dz * dz + dw * dw;
    }
    __shared__ float red[256];
    red[tid] = s;
    __syncthreads();
    for (int off = 128; off > 0; off >>= 1) {
        if (tid < off) red[tid] += red[tid + off];
        __syncthreads();
    }
    if (tid == 0) partials[blockIdx.x] = red[0];
}

// ---------- K2b: finalize diff ----------
__global__ __launch_bounds__(256) void k_diff(const float* __restrict__ partials,
                                              float* __restrict__ out_diff) {
    __shared__ float red[256];
    int tid = threadIdx.x;
    float s = 0.f;
    for (int j = 0; j < 8; j++) s += partials[tid * 8 + j];
    red[tid] = s;
    __syncthreads();
    for (int off = 128; off > 0; off >>= 1) {
        if (tid < off) red[tid] += red[tid + off];
        __syncthreads();
    }
    if (tid == 0) out_diff[0] = red[0] / 16777216.0f;
}

// ---------- K3: histogram of assignments ----------
__global__ __launch_bounds__(256) void k_hist(const int* __restrict__ ind,
                                              int* __restrict__ counts) {
    __shared__ int h[NEMB];
    int tid = threadIdx.x;
    for (int j = tid; j < NEMB; j += 256) h[j] = 0;
    __syncthreads();
    for (int i = blockIdx.x * 256 + tid; i < NROWS; i += 64 * 256)
        atomicAdd(&h[ind[i]], 1);
    __syncthreads();
    for (int j = tid; j < NEMB; j += 256)
        if (h[j]) atomicAdd(&counts[j], h[j]);
}

// ---------- K4: scans (row offsets + sub-chunk offsets); ncs, n, cs ----------
__global__ __launch_bounds__(1024) void k_scan(const int* __restrict__ counts,
                                               const float* __restrict__ cluster_size,
                                               int* __restrict__ offsets,
                                               int* __restrict__ cursor,
                                               int* __restrict__ substart,
                                               float* __restrict__ out_ncs,
                                               float* __restrict__ cs) {
    __shared__ int sh[NEMB];
    __shared__ float shf[NEMB];
    int tid = threadIdx.x;
    int c = counts[tid];
    sh[tid] = c;
    __syncthreads();
    for (int off = 1; off < NEMB; off <<= 1) {
        int t = (tid >= off) ? sh[tid - off] : 0;
        __syncthreads();
        sh[tid] += t;
        __syncthreads();
    }
    int excl = sh[tid] - c;
    offsets[tid] = excl;
    cursor[tid]  = excl;
    int sc = (c + CH - 1) / CH;
    __syncthreads();
    sh[tid] = sc;
    __syncthreads();
    for (int off = 1; off < NEMB; off <<= 1) {
        int t = (tid >= off) ? sh[tid - off] : 0;
        __syncthreads();
        sh[tid] += t;
        __syncthreads();
    }
    substart[tid] = sh[tid] - sc;
    if (tid == NEMB - 1) substart[NEMB] = sh[tid];
    float ncs = cluster_size[tid] * DECAY + (1.f - DECAY) * (float)c;
    out_ncs[tid] = ncs;
    shf[tid] = ncs;
    __syncthreads();
    for (int off = 512; off > 0; off >>= 1) {
        if (tid < off) shf[tid] += shf[tid + off];
        __syncthreads();
    }
    float n = shf[0];
    cs[tid] = (ncs + EPS) / (n + NEMB * EPS) * n;
}

// ---------- K5: scatter rows by cluster ----------
__global__ __launch_bounds__(256) void k_scatter(const int* __restrict__ ind,
                                                 int* __restrict__ cursor,
                                                 int* __restrict__ sorted) {
    int i = blockIdx.x * 256 + threadIdx.x;
    int k = ind[i];
    int pos = atomicAdd(&cursor[k], 1);
    sorted[pos] = i;
}

// ---------- K6a: balanced partial sums. block = one 64-row sub-chunk ----------
__global__ __launch_bounds__(256) void k_psum(const float* __restrict__ input,
                                              const int* __restrict__ sorted,
                                              const int* __restrict__ counts,
                                              const int* __restrict__ offsets,
                                              const int* __restrict__ substart,
                                              float* __restrict__ partial) {
    const int b = blockIdx.x;
    if (b >= substart[NEMB]) return;
    int lo = 0, hi = NEMB;
    while (hi - lo > 1) {
        int mid = (lo + hi) >> 1;
        if (substart[mid] <= b) lo = mid; else hi = mid;
    }
    const int k     = lo;
    const int chunk = b - substart[k];
    const int cnt   = counts[k];
    const int base  = offsets[k] + chunk * CH;
    const int lim   = min(CH, cnt - chunk * CH);
    const int d     = threadIdx.x;
    float s = 0.f;
    for (int i = 0; i < lim; i++) {
        int row = sorted[base + i];
        s += input[(size_t)row * DIM + d];
    }
    partial[(size_t)b * DIM + d] = s;
}

// ---------- K6b: per-cluster combine (fixed order) + EMA + new_embed ----------
__global__ __launch_bounds__(256) void k_ema(const float* __restrict__ partial,
                                             const float* __restrict__ embed_avg,
                                             const int* __restrict__ substart,
                                             const float* __restrict__ cs,
                                             float* __restrict__ out_navg,
                                             float* __restrict__ out_nembed) {
    const int d = blockIdx.x;
    const int t = threadIdx.x;
#pragma unroll
    for (int i = 0; i < 4; i++) {
        int k = t + 256 * i;
        int s0 = substart[k], s1 = substart[k + 1];
        float s = 0.f;
        for (int sub = s0; sub < s1; sub++)
            s += partial[(size_t)sub * DIM + d];
        float navg = embed_avg[(size_t)d * NEMB + k] * (DECAY * DECAY) + (1.f - DECAY) * s;
        out_navg[(size_t)d * NEMB + k] = navg;
        out_nembed[(size_t)d * NEMB + k] = navg / cs[k];
    }
}

extern "C" void kernel_launch(void* const* d_in, const int* in_sizes, int n_in,
                              void* d_out, int out_size, void* d_ws, size_t ws_size,
                              hipStream_t stream) {
    const float* input        = (const float*)d_in[0];
    const float* embed        = (const float*)d_in[1];
    const float* cluster_size = (const float*)d_in[2];
    const float* embed_avg    = (const float*)d_in[3];

    float* out        = (float*)d_out;
    float* out_q      = out;                       // 16777216
    float* out_diff   = out + 16777216;            // 1
    float* out_ind    = out + 16777217;            // 65536
    float* out_ncs    = out + 16842753;            // 1024
    float* out_navg   = out + 16843777;            // 262144
    float* out_nembed = out + 17105921;            // 262144

    char* ws = (char*)d_ws;
    size_t o = 0;
    int*   w_ind      = (int*)(ws + o);   o += (size_t)NROWS * 4;
    float* w_embedT   = (float*)(ws + o); o += (size_t)DIM * NEMB * 4;
    float* w_enorm    = (float*)(ws + o); o += NEMB * 4;
    int*   w_counts   = (int*)(ws + o);   o += NEMB * 4;
    int*   w_offsets  = (int*)(ws + o);   o += NEMB * 4;
    int*   w_cursor   = (int*)(ws + o);   o += NEMB * 4;
    float* w_cs       = (float*)(ws + o); o += NEMB * 4;
    float* w_partials = (float*)(ws + o); o += 2048 * 4;
    int*   w_sorted   = (int*)(ws + o);   o += (size_t)NROWS * 4;
    int*   w_substart = (int*)(ws + o);   o += (NEMB + 4) * 4;
    float* w_partial  = (float*)(ws + o); o += (size_t)MAXSUB * DIM * 4;
    f16*   w_ehlT     = (f16*)(ws + o);   o += (size_t)NEMB * 512 * 2;

    k_enorm<<<16, 256, 0, stream>>>(embed, w_enorm, w_counts);
    k_transpose<<<dim3(32, 8), dim3(32, 8), 0, stream>>>(embed, w_embedT);
    k_esplit<<<dim3(32, 8), dim3(32, 8), 0, stream>>>(embed, w_ehlT);
    k_argmin_mfma<<<NROWS / 128, 256, 0, stream>>>(input, w_ehlT, w_enorm, w_ind, out_ind);
    k_quant<<<2048, 256, 0, stream>>>(input, w_embedT, w_ind, out_q, w_partials);
    k_diff<<<1, 256, 0, stream>>>(w_partials, out_diff);
    k_hist<<<64, 256, 0, stream>>>(w_ind, w_counts);
    k_scan<<<1, 1024, 0, stream>>>(w_counts, cluster_size, w_offsets, w_cursor,
                                   w_substart, out_ncs, w_cs);
    k_scatter<<<NROWS / 256, 256, 0, stream>>>(w_ind, w_cursor, w_sorted);
    k_psum<<<MAXSUB, 256, 0, stream>>>(input, w_sorted, w_counts, w_offsets,
                                       w_substart, w_partial);
    k_ema<<<DIM, 256, 0, stream>>>(w_partial, embed_avg, w_substart, w_cs,
                                   out_navg, out_nembed);
}

// Round 5
// 306.497 us; speedup vs baseline: 1.4795x; 1.4795x over previous
//
#include <hip/hip_runtime.h>
#include <float.h>

#define DECAY 0.99f
#define EPS 1e-5f
#define NROWS 65536
#define DIM 256
#define NEMB 1024
#define CH 64            // rows per sub-chunk in segmented reduction
#define MAXSUB 2048      // NROWS/CH + NEMB upper bound on total sub-chunks

typedef _Float16 f16;
typedef _Float16 half8 __attribute__((ext_vector_type(8)));
typedef float f32x4 __attribute__((ext_vector_type(4)));

// ---------- K0a: ||e_k||^2 per code + zero counts ----------
__global__ __launch_bounds__(256) void k_enorm(const float* __restrict__ embed,
                                               float* __restrict__ enorm2,
                                               int* __restrict__ counts) {
    int kk = threadIdx.x & 63;
    int dg = threadIdx.x >> 6;              // 0..3
    int k  = blockIdx.x * 64 + kk;          // 16 blocks * 64 = 1024 codes
    float s = 0.f;
    for (int d = dg; d < DIM; d += 4) {
        float v = embed[(size_t)d * NEMB + k];
        s = fmaf(v, v, s);
    }
    __shared__ float red[4][64];
    red[dg][kk] = s;
    __syncthreads();
    if (dg == 0) enorm2[k] = red[0][kk] + red[1][kk] + red[2][kk] + red[3][kk];
    int gt = blockIdx.x * 256 + threadIdx.x;
    if (gt < NEMB) counts[gt] = 0;
}

// ---------- K0b: transpose embed [256][1024] -> embedT [1024][256] (for k_quant) ----------
__global__ __launch_bounds__(256) void k_transpose(const float* __restrict__ embed,
                                                   float* __restrict__ embedT) {
    __shared__ float tile[32][33];
    int k0 = blockIdx.x * 32, d0 = blockIdx.y * 32;
    int tx = threadIdx.x, ty = threadIdx.y;  // 32 x 8
#pragma unroll
    for (int i = 0; i < 4; i++)
        tile[ty + 8 * i][tx] = embed[(size_t)(d0 + ty + 8 * i) * NEMB + k0 + tx];
    __syncthreads();
#pragma unroll
    for (int i = 0; i < 4; i++)
        embedT[(size_t)(k0 + ty + 8 * i) * DIM + d0 + tx] = tile[tx][ty + 8 * i];
}

// ---------- K0c: embed fp32 [256][1024] -> ehlT f16 [1024][512] ([c][0:256]=hi, [c][256:512]=lo) ----------
__global__ __launch_bounds__(256) void k_esplit(const float* __restrict__ embed,
                                                f16* __restrict__ ehlT) {
    __shared__ float tile[32][33];           // [d-local][c-local]
    int c0 = blockIdx.x * 32, d0 = blockIdx.y * 32;
    int tx = threadIdx.x, ty = threadIdx.y;  // 32 x 8
#pragma unroll
    for (int i = 0; i < 4; i++)
        tile[ty + 8 * i][tx] = embed[(size_t)(d0 + ty + 8 * i) * NEMB + c0 + tx];
    __syncthreads();
#pragma unroll
    for (int i = 0; i < 4; i++) {
        int c = c0 + ty + 8 * i;
        int d = d0 + tx;
        float v = tile[tx][ty + 8 * i];
        f16 h = (f16)v;
        f16 l = (f16)(v - (float)h);
        ehlT[(size_t)c * 512 + d]       = h;
        ehlT[(size_t)c * 512 + 256 + d] = l;
    }
}

// ---------- K1: MFMA GEMM-argmin v3 ----------
// 512 threads = 8 waves (2 row x 4 col), block = 128 rows x 1024 cols.
// A resident: [128 rows][512 f16] = 128KB (row*1024B, 64 slots of 16B,
//             byte = row*1024 + ((slot*16) ^ ((row&7)<<4)); k-phys 0..255=xh, 256..511=xl).
// B tile: 256 cols x 32 k = 16KB single buffer (T14 reg-prefetch),
//             byte = col*64 + ((slot*16) ^ (((col>>1)&3)<<4)).
// K order per ct: kt 0-7 xh*eh, 8-15 xl*eh, 16-23 xh*el (effective K=768).
#define LDS_A  0
#define LDS_B  131072
#define LDS_SZ 147456

__global__ __launch_bounds__(512, 2) void k_argmin_mfma(const float* __restrict__ input,
                                                        const f16* __restrict__ ehlT,
                                                        const float* __restrict__ enorm2,
                                                        int* __restrict__ ind,
                                                        float* __restrict__ out_ind) {
    __shared__ char lds[LDS_SZ];
    const int tid  = threadIdx.x;
    const int lane = tid & 63;
    const int w    = tid >> 6;        // wave 0..7
    const int wr   = w >> 2;          // 0/1 : rows wr*64..+64
    const int wc   = w & 3;           // 0..3: cols wc*64..+64 within 256-slab
    const int rb   = blockIdx.x * 128;
    const int l15  = lane & 15;
    const int lkh  = lane >> 4;       // 0..3
    const int swa  = (l15 & 7) << 4;
    const int swb  = ((l15 >> 1) & 3) << 4;

    // ---- stage A once: 128 rows x 256 d fp32 -> hi/lo f16, swizzled ----
#pragma unroll
    for (int it8 = 0; it8 < 4; it8++) {
        int task = tid + 512 * it8;          // 0..2047
        int row = task >> 4, ch = task & 15; // ch = 16-d chunk
        const float4* g = (const float4*)(input + (size_t)(rb + row) * DIM + ch * 16);
        float fv[16];
        *(float4*)(fv + 0)  = g[0];
        *(float4*)(fv + 4)  = g[1];
        *(float4*)(fv + 8)  = g[2];
        *(float4*)(fv + 12) = g[3];
        half8 hh[2], llv[2];
#pragma unroll
        for (int u = 0; u < 2; u++)
#pragma unroll
            for (int e = 0; e < 8; e++) {
                float x = fv[u * 8 + e];
                f16 h = (f16)x;
                hh[u][e]  = h;
                llv[u][e] = (f16)(x - (float)h);
            }
        int rbase = row * 1024;
        int sw = (row & 7) << 4;
        *(half8*)(lds + LDS_A + rbase + (((ch * 2    ) * 16) ^ sw)) = hh[0];
        *(half8*)(lds + LDS_A + rbase + (((ch * 2 + 1) * 16) ^ sw)) = hh[1];
        *(half8*)(lds + LDS_A + rbase + (((32 + ch * 2) * 16) ^ sw)) = llv[0];
        *(half8*)(lds + LDS_A + rbase + (((33 + ch * 2) * 16) ^ sw)) = llv[1];
    }

    // ---- B prologue: tile (ct=0, kt=0): cols 0..255, k 0..31 of eh ----
#pragma unroll
    for (int u = 0; u < 2; u++) {
        int g = tid + 512 * u;               // 0..1023
        int col = g >> 2, s = g & 3;
        half8 h = *(const half8*)(ehlT + (size_t)col * 512 + s * 8);
        *(half8*)(lds + LDS_B + col * 64 + ((s * 16) ^ (((col >> 1) & 3) << 4))) = h;
    }
    __syncthreads();

    float bv[16];
    int   bi[16];
#pragma unroll
    for (int q = 0; q < 16; q++) { bv[q] = FLT_MAX; bi[q] = 0x7fffffff; }

    for (int ct = 0; ct < 4; ct++) {
        const int cb = ct * 256;
        f32x4 acc[4][4];
#pragma unroll
        for (int fr = 0; fr < 4; fr++)
#pragma unroll
            for (int fc = 0; fc < 4; fc++) acc[fr][fc] = (f32x4){0.f, 0.f, 0.f, 0.f};

        for (int kt = 0; kt < 24; kt++) {
            const int it = ct * 24 + kt;
            const bool hn = (it < 95);
            // ---- prefetch next B tile into regs (issue-early) ----
            float4 nb0, nb1;
            int wa0 = 0, wa1 = 0;
            if (hn) {
                int itn = it + 1;
                int ct2 = itn / 24;
                int kt2 = itn - ct2 * 24;
                int seg2 = kt2 >> 3, kq2 = kt2 & 7;
                int koff2 = ((seg2 == 2) ? 256 : 0) + kq2 * 32;
                int cb2 = ct2 * 256;
                int g0 = tid, col0 = g0 >> 2, s0 = g0 & 3;
                nb0 = *(const float4*)(ehlT + (size_t)(cb2 + col0) * 512 + koff2 + s0 * 8);
                wa0 = col0 * 64 + ((s0 * 16) ^ (((col0 >> 1) & 3) << 4));
                int g1 = tid + 512, col1 = g1 >> 2, s1 = g1 & 3;
                nb1 = *(const float4*)(ehlT + (size_t)(cb2 + col1) * 512 + koff2 + s1 * 8);
                wa1 = col1 * 64 + ((s1 * 16) ^ (((col1 >> 1) & 3) << 4));
            }
            // ---- MFMA on current tile ----
            const int seg = kt >> 3, kq = kt & 7;
            const int abase = ((seg == 1) ? 32 : 0) + kq * 4;
            const int jslot = abase + lkh;
            half8 af[4], bf[4];
#pragma unroll
            for (int f = 0; f < 4; f++) {
                int row = wr * 64 + f * 16 + l15;
                af[f] = *(const half8*)(lds + LDS_A + row * 1024 + ((jslot * 16) ^ swa));
            }
#pragma unroll
            for (int f = 0; f < 4; f++) {
                int col = wc * 64 + f * 16 + l15;
                bf[f] = *(const half8*)(lds + LDS_B + col * 64 + ((lkh * 16) ^ swb));
            }
#pragma unroll
            for (int fr = 0; fr < 4; fr++)
#pragma unroll
                for (int fc = 0; fc < 4; fc++)
                    acc[fr][fc] = __builtin_amdgcn_mfma_f32_16x16x32_f16(
                        af[fr], bf[fc], acc[fr][fc], 0, 0, 0);
            // ---- slab epilogue: running argmin ----
            if (kt == 23) {
#pragma unroll
                for (int fc = 0; fc < 4; fc++) {
                    int col = cb + wc * 64 + fc * 16 + l15;
                    float e2 = enorm2[col];
#pragma unroll
                    for (int fr = 0; fr < 4; fr++)
#pragma unroll
                        for (int r = 0; r < 4; r++) {
                            float s = fmaf(-2.f, acc[fr][fc][r], e2);
                            int q = fr * 4 + r;
                            if (s < bv[q]) { bv[q] = s; bi[q] = col; }
                        }
                }
            }
            __syncthreads();                 // all reads of B done
            if (hn) {
                *(half8*)(lds + LDS_B + wa0) = *(half8*)&nb0;
                *(half8*)(lds + LDS_B + wa1) = *(half8*)&nb1;
            }
            __syncthreads();                 // B writes visible
        }
    }

    // ---- cross-lane reduce: min over the 16 col-lanes (same lkh group) ----
#pragma unroll
    for (int q = 0; q < 16; q++) {
        float v = bv[q]; int i = bi[q];
#pragma unroll
        for (int m = 1; m <= 8; m <<= 1) {
            float ov = __shfl_xor(v, m, 64);
            int   oi = __shfl_xor(i, m, 64);
            if (ov < v || (ov == v && oi < i)) { v = ov; i = oi; }
        }
        bv[q] = v; bi[q] = i;
    }
    // overlay PV/PI on B buffer (no further B reads)
    float* PV = (float*)(lds + LDS_B);          // [128][4]
    int*   PI = (int*)(lds + LDS_B + 2048);     // [128][4]
    if (l15 == 0) {
#pragma unroll
        for (int fr = 0; fr < 4; fr++)
#pragma unroll
            for (int r = 0; r < 4; r++) {
                int rrow = wr * 64 + fr * 16 + lkh * 4 + r;
                PV[rrow * 4 + wc] = bv[fr * 4 + r];
                PI[rrow * 4 + wc] = bi[fr * 4 + r];
            }
    }
    __syncthreads();
    if (tid < 128) {
        float best = FLT_MAX; int bidx = 0x7fffffff;
#pragma unroll
        for (int t = 0; t < 4; t++) {
            float v = PV[tid * 4 + t];
            int   i = PI[tid * 4 + t];
            if (v < best || (v == best && i < bidx)) { best = v; bidx = i; }
        }
        ind[rb + tid] = bidx;
        out_ind[rb + tid] = (float)bidx;
    }
}

// ---------- K2: quantize_st output + per-block diff partials ----------
__global__ __launch_bounds__(256) void k_quant(const float* __restrict__ input,
                                               const float* __restrict__ embedT,
                                               const int* __restrict__ ind,
                                               float* __restrict__ out_q,
                                               float* __restrict__ partials) {
    const int tid = threadIdx.x;
    const unsigned gid = blockIdx.x * 256 + tid;
    float s = 0.f;
#pragma unroll
    for (int j = 0; j < 8; j++) {
        size_t i4 = (size_t)gid + (size_t)j * 524288u;   // 4194304 float4 total
        int row = (int)(i4 >> 6);
        int d4  = (int)(i4 & 63);
        float4 iv = *reinterpret_cast<const float4*>(input + i4 * 4);
        int k = ind[row];
        float4 qv = *reinterpret_cast<const float4*>(embedT + (size_t)k * DIM + d4 * 4);
        float dx = qv.x - iv.x, dy = qv.y - iv.y, dz = qv.z - iv.z, dw = qv.w - iv.w;
        float4 ov;
        ov.x = iv.x + dx; ov.y = iv.y + dy; ov.z = iv.z + dz; ov.w = iv.w + dw;
        *reinterpret_cast<float4*>(out_q + i4 * 4) = ov;
        s += dx * dx + dy * dy + dz * dz + dw * dw;
    }
    __shared__ float red[256];
    red[tid] = s;
    __syncthreads();
    for (int off = 128; off > 0; off >>= 1) {
        if (tid < off) red[tid] += red[tid + off];
        __syncthreads();
    }
    if (tid == 0) partials[blockIdx.x] = red[0];
}

// ---------- K2b: finalize diff ----------
__global__ __launch_bounds__(256) void k_diff(const float* __restrict__ partials,
                                              float* __restrict__ out_diff) {
    __shared__ float red[256];
    int tid = threadIdx.x;
    float s = 0.f;
    for (int j = 0; j < 8; j++) s += partials[tid * 8 + j];
    red[tid] = s;
    __syncthreads();
    for (int off = 128; off > 0; off >>= 1) {
        if (tid < off) red[tid] += red[tid + off];
        __syncthreads();
    }
    if (tid == 0) out_diff[0] = red[0] / 16777216.0f;
}

// ---------- K3: histogram of assignments ----------
__global__ __launch_bounds__(256) void k_hist(const int* __restrict__ ind,
                                              int* __restrict__ counts) {
    __shared__ int h[NEMB];
    int tid = threadIdx.x;
    for (int j = tid; j < NEMB; j += 256) h[j] = 0;
    __syncthreads();
    for (int i = blockIdx.x * 256 + tid; i < NROWS; i += 64 * 256)
        atomicAdd(&h[ind[i]], 1);
    __syncthreads();
    for (int j = tid; j < NEMB; j += 256)
        if (h[j]) atomicAdd(&counts[j], h[j]);
}

// ---------- K4: scans (row offsets + sub-chunk offsets); ncs, n, cs ----------
__global__ __launch_bounds__(1024) void k_scan(const int* __restrict__ counts,
                                               const float* __restrict__ cluster_size,
                                               int* __restrict__ offsets,
                                               int* __restrict__ cursor,
                                               int* __restrict__ substart,
                                               float* __restrict__ out_ncs,
                                               float* __restrict__ cs) {
    __shared__ int sh[NEMB];
    __shared__ float shf[NEMB];
    int tid = threadIdx.x;
    int c = counts[tid];
    sh[tid] = c;
    __syncthreads();
    for (int off = 1; off < NEMB; off <<= 1) {
        int t = (tid >= off) ? sh[tid - off] : 0;
        __syncthreads();
        sh[tid] += t;
        __syncthreads();
    }
    int excl = sh[tid] - c;
    offsets[tid] = excl;
    cursor[tid]  = excl;
    int sc = (c + CH - 1) / CH;
    __syncthreads();
    sh[tid] = sc;
    __syncthreads();
    for (int off = 1; off < NEMB; off <<= 1) {
        int t = (tid >= off) ? sh[tid - off] : 0;
        __syncthreads();
        sh[tid] += t;
        __syncthreads();
    }
    substart[tid] = sh[tid] - sc;
    if (tid == NEMB - 1) substart[NEMB] = sh[tid];
    float ncs = cluster_size[tid] * DECAY + (1.f - DECAY) * (float)c;
    out_ncs[tid] = ncs;
    shf[tid] = ncs;
    __syncthreads();
    for (int off = 512; off > 0; off >>= 1) {
        if (tid < off) shf[tid] += shf[tid + off];
        __syncthreads();
    }
    float n = shf[0];
    cs[tid] = (ncs + EPS) / (n + NEMB * EPS) * n;
}

// ---------- K5: scatter rows by cluster ----------
__global__ __launch_bounds__(256) void k_scatter(const int* __restrict__ ind,
                                                 int* __restrict__ cursor,
                                                 int* __restrict__ sorted) {
    int i = blockIdx.x * 256 + threadIdx.x;
    int k = ind[i];
    int pos = atomicAdd(&cursor[k], 1);
    sorted[pos] = i;
}

// ---------- K6a: balanced partial sums. block = one 64-row sub-chunk ----------
__global__ __launch_bounds__(256) void k_psum(const float* __restrict__ input,
                                              const int* __restrict__ sorted,
                                              const int* __restrict__ counts,
                                              const int* __restrict__ offsets,
                                              const int* __restrict__ substart,
                                              float* __restrict__ partial) {
    const int b = blockIdx.x;
    if (b >= substart[NEMB]) return;
    int lo = 0, hi = NEMB;
    while (hi - lo > 1) {
        int mid = (lo + hi) >> 1;
        if (substart[mid] <= b) lo = mid; else hi = mid;
    }
    const int k     = lo;
    const int chunk = b - substart[k];
    const int cnt   = counts[k];
    const int base  = offsets[k] + chunk * CH;
    const int lim   = min(CH, cnt - chunk * CH);
    const int d     = threadIdx.x;
    float s = 0.f;
    for (int i = 0; i < lim; i++) {
        int row = sorted[base + i];
        s += input[(size_t)row * DIM + d];
    }
    partial[(size_t)b * DIM + d] = s;
}

// ---------- K6b: per-cluster combine (fixed order) + EMA + new_embed ----------
__global__ __launch_bounds__(256) void k_ema(const float* __restrict__ partial,
                                             const float* __restrict__ embed_avg,
                                             const int* __restrict__ substart,
                                             const float* __restrict__ cs,
                                             float* __restrict__ out_navg,
                                             float* __restrict__ out_nembed) {
    const int d = blockIdx.x;
    const int t = threadIdx.x;
#pragma unroll
    for (int i = 0; i < 4; i++) {
        int k = t + 256 * i;
        int s0 = substart[k], s1 = substart[k + 1];
        float s = 0.f;
        for (int sub = s0; sub < s1; sub++)
            s += partial[(size_t)sub * DIM + d];
        float navg = embed_avg[(size_t)d * NEMB + k] * (DECAY * DECAY) + (1.f - DECAY) * s;
        out_navg[(size_t)d * NEMB + k] = navg;
        out_nembed[(size_t)d * NEMB + k] = navg / cs[k];
    }
}

extern "C" void kernel_launch(void* const* d_in, const int* in_sizes, int n_in,
                              void* d_out, int out_size, void* d_ws, size_t ws_size,
                              hipStream_t stream) {
    const float* input        = (const float*)d_in[0];
    const float* embed        = (const float*)d_in[1];
    const float* cluster_size = (const float*)d_in[2];
    const float* embed_avg    = (const float*)d_in[3];

    float* out        = (float*)d_out;
    float* out_q      = out;                       // 16777216
    float* out_diff   = out + 16777216;            // 1
    float* out_ind    = out + 16777217;            // 65536
    float* out_ncs    = out + 16842753;            // 1024
    float* out_navg   = out + 16843777;            // 262144
    float* out_nembed = out + 17105921;            // 262144

    char* ws = (char*)d_ws;
    size_t o = 0;
    int*   w_ind      = (int*)(ws + o);   o += (size_t)NROWS * 4;
    float* w_embedT   = (float*)(ws + o); o += (size_t)DIM * NEMB * 4;
    float* w_enorm    = (float*)(ws + o); o += NEMB * 4;
    int*   w_counts   = (int*)(ws + o);   o += NEMB * 4;
    int*   w_offsets  = (int*)(ws + o);   o += NEMB * 4;
    int*   w_cursor   = (int*)(ws + o);   o += NEMB * 4;
    float* w_cs       = (float*)(ws + o); o += NEMB * 4;
    float* w_partials = (float*)(ws + o); o += 2048 * 4;
    int*   w_sorted   = (int*)(ws + o);   o += (size_t)NROWS * 4;
    int*   w_substart = (int*)(ws + o);   o += (NEMB + 4) * 4;
    float* w_partial  = (float*)(ws + o); o += (size_t)MAXSUB * DIM * 4;
    f16*   w_ehlT     = (f16*)(ws + o);   o += (size_t)NEMB * 512 * 2;

    k_enorm<<<16, 256, 0, stream>>>(embed, w_enorm, w_counts);
    k_transpose<<<dim3(32, 8), dim3(32, 8), 0, stream>>>(embed, w_embedT);
    k_esplit<<<dim3(32, 8), dim3(32, 8), 0, stream>>>(embed, w_ehlT);
    k_argmin_mfma<<<NROWS / 128, 512, 0, stream>>>(input, w_ehlT, w_enorm, w_ind, out_ind);
    k_quant<<<2048, 256, 0, stream>>>(input, w_embedT, w_ind, out_q, w_partials);
    k_diff<<<1, 256, 0, stream>>>(w_partials, out_diff);
    k_hist<<<64, 256, 0, stream>>>(w_ind, w_counts);
    k_scan<<<1, 1024, 0, stream>>>(w_counts, cluster_size, w_offsets, w_cursor,
                                   w_substart, out_ncs, w_cs);
    k_scatter<<<NROWS / 256, 256, 0, stream>>>(w_ind, w_cursor, w_sorted);
    k_psum<<<MAXSUB, 256, 0, stream>>>(input, w_sorted, w_counts, w_offsets,
                                       w_substart, w_partial);
    k_ema<<<DIM, 256, 0, stream>>>(w_partial, embed_avg, w_substart, w_cs,
                                   out_navg, out_nembed);
}

// Round 6
// 294.204 us; speedup vs baseline: 1.5413x; 1.0418x over previous
//
#include <hip/hip_runtime.h>
#include <float.h>

#define DECAY 0.99f
#define EPS 1e-5f
#define NROWS 65536
#define DIM 256
#define NEMB 1024
#define CH 64            // rows per sub-chunk in segmented reduction
#define MAXSUB 2048      // NROWS/CH + NEMB upper bound on total sub-chunks

#define GLOBAL_AS __attribute__((address_space(1)))
#define LOCAL_AS  __attribute__((address_space(3)))

typedef _Float16 f16;
typedef _Float16 half8 __attribute__((ext_vector_type(8)));
typedef float f32x4 __attribute__((ext_vector_type(4)));

// ---------- K0a: ||e_k||^2 per code + zero counts ----------
__global__ __launch_bounds__(256) void k_enorm(const float* __restrict__ embed,
                                               float* __restrict__ enorm2,
                                               int* __restrict__ counts) {
    int kk = threadIdx.x & 63;
    int dg = threadIdx.x >> 6;              // 0..3
    int k  = blockIdx.x * 64 + kk;          // 16 blocks * 64 = 1024 codes
    float s = 0.f;
    for (int d = dg; d < DIM; d += 4) {
        float v = embed[(size_t)d * NEMB + k];
        s = fmaf(v, v, s);
    }
    __shared__ float red[4][64];
    red[dg][kk] = s;
    __syncthreads();
    if (dg == 0) enorm2[k] = red[0][kk] + red[1][kk] + red[2][kk] + red[3][kk];
    int gt = blockIdx.x * 256 + threadIdx.x;
    if (gt < NEMB) counts[gt] = 0;
}

// ---------- K0b: fused transpose (embedT fp32) + hi/lo split (ehlT f16) ----------
__global__ __launch_bounds__(256) void k_prep(const float* __restrict__ embed,
                                              float* __restrict__ embedT,
                                              f16* __restrict__ ehlT) {
    __shared__ float tile[32][33];           // [d-local][c-local]
    int c0 = blockIdx.x * 32, d0 = blockIdx.y * 32;
    int tx = threadIdx.x, ty = threadIdx.y;  // 32 x 8
#pragma unroll
    for (int i = 0; i < 4; i++)
        tile[ty + 8 * i][tx] = embed[(size_t)(d0 + ty + 8 * i) * NEMB + c0 + tx];
    __syncthreads();
#pragma unroll
    for (int i = 0; i < 4; i++) {
        int c = c0 + ty + 8 * i;
        int d = d0 + tx;
        float v = tile[tx][ty + 8 * i];
        embedT[(size_t)c * DIM + d] = v;
        f16 h = (f16)v;
        ehlT[(size_t)c * 512 + d]       = h;
        ehlT[(size_t)c * 512 + 256 + d] = (f16)(v - (float)h);
    }
}

// ---------- K1: MFMA GEMM-argmin v4 ----------
// 512 threads = 8 waves (2 row x 4 col), block = 128 rows x 1024 cols.
// A resident: [128 rows][512 f16] = 128KB, byte = row*1024 + ((slot*16)^((row&7)<<4)).
// B: double-buffered 16KB tiles (256 cols x 32 k), filled by global_load_lds
//    (linear dest, pre-swizzled per-lane source: slot_log = (l&3)^((l>>3)&3)),
//    read at byte = col*64 + ((lkh*16) ^ (((col>>1)&3)<<4)).
// ONE __syncthreads per K-step: its vmcnt(0) drain lands the prefetch issued
// at the top of the step (hidden under the 16-MFMA phase).
#define LDS_A  0
#define LDS_B0 131072
#define LDS_B1 147456
#define LDS_SZ 163840

__global__ __launch_bounds__(512, 2) void k_argmin_mfma(const float* __restrict__ input,
                                                        const f16* __restrict__ ehlT,
                                                        const float* __restrict__ enorm2,
                                                        int* __restrict__ ind,
                                                        float* __restrict__ out_ind) {
    __shared__ char lds[LDS_SZ];
    const int tid  = threadIdx.x;
    const int lane = tid & 63;
    const int w    = tid >> 6;        // wave 0..7
    const int wr   = w >> 2;          // 0/1 : rows wr*64..+64
    const int wc   = w & 3;           // 0..3: cols wc*64..+64 within 256-slab
    const int rb   = blockIdx.x * 128;
    const int l15  = lane & 15;
    const int lkh  = lane >> 4;       // 0..3
    const int swa  = (l15 & 7) << 4;
    const int swb  = ((l15 >> 1) & 3) << 4;
    // per-lane global-source offset (f16 units) for B prefetch within a 16-col chunk
    const int slot_log   = (lane & 3) ^ ((lane >> 3) & 3);
    const int gl_laneoff = (lane >> 2) * 512 + slot_log * 8;

    // ---- issue B tile 0 prefetch (it=0: ct2=0, koff=0) ----
#pragma unroll
    for (int i = 0; i < 2; i++) {
        int chunkid = w * 2 + i;
        const f16* src = ehlT + (size_t)chunkid * 8192 + gl_laneoff;
        __builtin_amdgcn_global_load_lds((const GLOBAL_AS unsigned*)src,
            (LOCAL_AS unsigned*)(lds + LDS_B0 + chunkid * 1024), 16, 0, 0);
    }

    // ---- stage A once: 128 rows x 256 d fp32 -> hi/lo f16, swizzled ----
#pragma unroll
    for (int it8 = 0; it8 < 4; it8++) {
        int task = tid + 512 * it8;          // 0..2047
        int row = task >> 4, ch = task & 15; // ch = 16-d chunk
        const float4* g = (const float4*)(input + (size_t)(rb + row) * DIM + ch * 16);
        float fv[16];
        *(float4*)(fv + 0)  = g[0];
        *(float4*)(fv + 4)  = g[1];
        *(float4*)(fv + 8)  = g[2];
        *(float4*)(fv + 12) = g[3];
        half8 hh[2], llv[2];
#pragma unroll
        for (int u = 0; u < 2; u++)
#pragma unroll
            for (int e = 0; e < 8; e++) {
                float x = fv[u * 8 + e];
                f16 h = (f16)x;
                hh[u][e]  = h;
                llv[u][e] = (f16)(x - (float)h);
            }
        int rbase = row * 1024;
        int sw = (row & 7) << 4;
        *(half8*)(lds + LDS_A + rbase + (((ch * 2    ) * 16) ^ sw)) = hh[0];
        *(half8*)(lds + LDS_A + rbase + (((ch * 2 + 1) * 16) ^ sw)) = hh[1];
        *(half8*)(lds + LDS_A + rbase + (((32 + ch * 2) * 16) ^ sw)) = llv[0];
        *(half8*)(lds + LDS_A + rbase + (((33 + ch * 2) * 16) ^ sw)) = llv[1];
    }
    __syncthreads();   // A staged + B0 landed (vmcnt/lgkm drained)

    float bv[16];
    int   bi[16];
#pragma unroll
    for (int q = 0; q < 16; q++) { bv[q] = FLT_MAX; bi[q] = 0x7fffffff; }

    int p = 0;
    for (int ct = 0; ct < 4; ct++) {
        const int cb = ct * 256;
        f32x4 acc[4][4];
#pragma unroll
        for (int fr = 0; fr < 4; fr++)
#pragma unroll
            for (int fc = 0; fc < 4; fc++) acc[fr][fc] = (f32x4){0.f, 0.f, 0.f, 0.f};

        for (int kt = 0; kt < 24; kt++) {
            const int it = ct * 24 + kt;
            // ---- issue next-tile prefetch into the idle buffer ----
            if (it < 95) {
                int itn = it + 1;
                int ct2 = itn / 24;
                int kt2 = itn - ct2 * 24;
                int seg2 = kt2 >> 3, kq2 = kt2 & 7;
                int koff2 = ((seg2 == 2) ? 256 : 0) + kq2 * 32;
                const f16* base = ehlT + (size_t)ct2 * 131072 + koff2 + gl_laneoff;
                char* dstb = lds + (p ? LDS_B0 : LDS_B1);
#pragma unroll
                for (int i = 0; i < 2; i++) {
                    int chunkid = w * 2 + i;
                    __builtin_amdgcn_global_load_lds(
                        (const GLOBAL_AS unsigned*)(base + (size_t)chunkid * 8192),
                        (LOCAL_AS unsigned*)(dstb + chunkid * 1024), 16, 0, 0);
                }
            }
            // ---- MFMA on current tile ----
            const int seg = kt >> 3, kq = kt & 7;
            const int jslot = ((seg == 1) ? 32 : 0) + kq * 4 + lkh;
            const char* Bb = lds + (p ? LDS_B1 : LDS_B0);
            half8 af[4], bf[4];
#pragma unroll
            for (int f = 0; f < 4; f++) {
                int row = wr * 64 + f * 16 + l15;
                af[f] = *(const half8*)(lds + LDS_A + row * 1024 + ((jslot * 16) ^ swa));
            }
#pragma unroll
            for (int f = 0; f < 4; f++) {
                int col = wc * 64 + f * 16 + l15;
                bf[f] = *(const half8*)(Bb + col * 64 + ((lkh * 16) ^ swb));
            }
#pragma unroll
            for (int fr = 0; fr < 4; fr++)
#pragma unroll
                for (int fc = 0; fc < 4; fc++)
                    acc[fr][fc] = __builtin_amdgcn_mfma_f32_16x16x32_f16(
                        af[fr], bf[fc], acc[fr][fc], 0, 0, 0);
            // ---- slab epilogue: running argmin ----
            if (kt == 23) {
#pragma unroll
                for (int fc = 0; fc < 4; fc++) {
                    int col = cb + wc * 64 + fc * 16 + l15;
                    float e2 = enorm2[col];
#pragma unroll
                    for (int fr = 0; fr < 4; fr++)
#pragma unroll
                        for (int r = 0; r < 4; r++) {
                            float s = fmaf(-2.f, acc[fr][fc][r], e2);
                            int q = fr * 4 + r;
                            if (s < bv[q]) { bv[q] = s; bi[q] = col; }
                        }
                }
            }
            __syncthreads();   // reads of buf[p] done; prefetch into buf[p^1] landed
            p ^= 1;
        }
    }

    // ---- cross-lane reduce: min over the 16 col-lanes (same lkh group) ----
#pragma unroll
    for (int q = 0; q < 16; q++) {
        float v = bv[q]; int i = bi[q];
#pragma unroll
        for (int m = 1; m <= 8; m <<= 1) {
            float ov = __shfl_xor(v, m, 64);
            int   oi = __shfl_xor(i, m, 64);
            if (ov < v || (ov == v && oi < i)) { v = ov; i = oi; }
        }
        bv[q] = v; bi[q] = i;
    }
    // overlay PV/PI on B buffer (no further B reads)
    float* PV = (float*)(lds + LDS_B0);          // [128][4]
    int*   PI = (int*)(lds + LDS_B0 + 2048);     // [128][4]
    if (l15 == 0) {
#pragma unroll
        for (int fr = 0; fr < 4; fr++)
#pragma unroll
            for (int r = 0; r < 4; r++) {
                int rrow = wr * 64 + fr * 16 + lkh * 4 + r;
                PV[rrow * 4 + wc] = bv[fr * 4 + r];
                PI[rrow * 4 + wc] = bi[fr * 4 + r];
            }
    }
    __syncthreads();
    if (tid < 128) {
        float best = FLT_MAX; int bidx = 0x7fffffff;
#pragma unroll
        for (int t = 0; t < 4; t++) {
            float v = PV[tid * 4 + t];
            int   i = PI[tid * 4 + t];
            if (v < best || (v == best && i < bidx)) { best = v; bidx = i; }
        }
        ind[rb + tid] = bidx;
        out_ind[rb + tid] = (float)bidx;
    }
}

// ---------- K2: quantize_st output + per-block diff partials ----------
__global__ __launch_bounds__(256) void k_quant(const float* __restrict__ input,
                                               const float* __restrict__ embedT,
                                               const int* __restrict__ ind,
                                               float* __restrict__ out_q,
                                               float* __restrict__ partials) {
    const int tid = threadIdx.x;
    const unsigned gid = blockIdx.x * 256 + tid;
    float s = 0.f;
#pragma unroll
    for (int j = 0; j < 8; j++) {
        size_t i4 = (size_t)gid + (size_t)j * 524288u;   // 4194304 float4 total
        int row = (int)(i4 >> 6);
        int d4  = (int)(i4 & 63);
        float4 iv = *reinterpret_cast<const float4*>(input + i4 * 4);
        int k = ind[row];
        float4 qv = *reinterpret_cast<const float4*>(embedT + (size_t)k * DIM + d4 * 4);
        float dx = qv.x - iv.x, dy = qv.y - iv.y, dz = qv.z - iv.z, dw = qv.w - iv.w;
        float4 ov;
        ov.x = iv.x + dx; ov.y = iv.y + dy; ov.z = iv.z + dz; ov.w = iv.w + dw;
        *reinterpret_cast<float4*>(out_q + i4 * 4) = ov;
        s += dx * dx + dy * dy + dz * dz + dw * dw;
    }
    __shared__ float red[256];
    red[tid] = s;
    __syncthreads();
    for (int off = 128; off > 0; off >>= 1) {
        if (tid < off) red[tid] += red[tid + off];
        __syncthreads();
    }
    if (tid == 0) partials[blockIdx.x] = red[0];
}

// ---------- K2b: finalize diff ----------
__global__ __launch_bounds__(256) void k_diff(const float* __restrict__ partials,
                                              float* __restrict__ out_diff) {
    __shared__ float red[256];
    int tid = threadIdx.x;
    float s = 0.f;
    for (int j = 0; j < 8; j++) s += partials[tid * 8 + j];
    red[tid] = s;
    __syncthreads();
    for (int off = 128; off > 0; off >>= 1) {
        if (tid < off) red[tid] += red[tid + off];
        __syncthreads();
    }
    if (tid == 0) out_diff[0] = red[0] / 16777216.0f;
}

// ---------- K3: histogram of assignments ----------
__global__ __launch_bounds__(256) void k_hist(const int* __restrict__ ind,
                                              int* __restrict__ counts) {
    __shared__ int h[NEMB];
    int tid = threadIdx.x;
    for (int j = tid; j < NEMB; j += 256) h[j] = 0;
    __syncthreads();
    for (int i = blockIdx.x * 256 + tid; i < NROWS; i += 64 * 256)
        atomicAdd(&h[ind[i]], 1);
    __syncthreads();
    for (int j = tid; j < NEMB; j += 256)
        if (h[j]) atomicAdd(&counts[j], h[j]);
}

// ---------- K4: scans (row offsets + sub-chunk offsets); ncs, n, cs ----------
__global__ __launch_bounds__(1024) void k_scan(const int* __restrict__ counts,
                                               const float* __restrict__ cluster_size,
                                               int* __restrict__ offsets,
                                               int* __restrict__ cursor,
                                               int* __restrict__ substart,
                                               float* __restrict__ out_ncs,
                                               float* __restrict__ cs) {
    __shared__ int sh[NEMB];
    __shared__ float shf[NEMB];
    int tid = threadIdx.x;
    int c = counts[tid];
    sh[tid] = c;
    __syncthreads();
    for (int off = 1; off < NEMB; off <<= 1) {
        int t = (tid >= off) ? sh[tid - off] : 0;
        __syncthreads();
        sh[tid] += t;
        __syncthreads();
    }
    int excl = sh[tid] - c;
    offsets[tid] = excl;
    cursor[tid]  = excl;
    int sc = (c + CH - 1) / CH;
    __syncthreads();
    sh[tid] = sc;
    __syncthreads();
    for (int off = 1; off < NEMB; off <<= 1) {
        int t = (tid >= off) ? sh[tid - off] : 0;
        __syncthreads();
        sh[tid] += t;
        __syncthreads();
    }
    substart[tid] = sh[tid] - sc;
    if (tid == NEMB - 1) substart[NEMB] = sh[tid];
    float ncs = cluster_size[tid] * DECAY + (1.f - DECAY) * (float)c;
    out_ncs[tid] = ncs;
    shf[tid] = ncs;
    __syncthreads();
    for (int off = 512; off > 0; off >>= 1) {
        if (tid < off) shf[tid] += shf[tid + off];
        __syncthreads();
    }
    float n = shf[0];
    cs[tid] = (ncs + EPS) / (n + NEMB * EPS) * n;
}

// ---------- K5: scatter rows by cluster ----------
__global__ __launch_bounds__(256) void k_scatter(const int* __restrict__ ind,
                                                 int* __restrict__ cursor,
                                                 int* __restrict__ sorted) {
    int i = blockIdx.x * 256 + threadIdx.x;
    int k = ind[i];
    int pos = atomicAdd(&cursor[k], 1);
    sorted[pos] = i;
}

// ---------- K6a: balanced partial sums. block = one 64-row sub-chunk ----------
__global__ __launch_bounds__(256) void k_psum(const float* __restrict__ input,
                                              const int* __restrict__ sorted,
                                              const int* __restrict__ counts,
                                              const int* __restrict__ offsets,
                                              const int* __restrict__ substart,
                                              float* __restrict__ partial) {
    const int b = blockIdx.x;
    if (b >= substart[NEMB]) return;
    int lo = 0, hi = NEMB;
    while (hi - lo > 1) {
        int mid = (lo + hi) >> 1;
        if (substart[mid] <= b) lo = mid; else hi = mid;
    }
    const int k     = lo;
    const int chunk = b - substart[k];
    const int cnt   = counts[k];
    const int base  = offsets[k] + chunk * CH;
    const int lim   = min(CH, cnt - chunk * CH);
    const int d     = threadIdx.x;
    float s = 0.f;
    for (int i = 0; i < lim; i++) {
        int row = sorted[base + i];
        s += input[(size_t)row * DIM + d];
    }
    partial[(size_t)b * DIM + d] = s;
}

// ---------- K6b: per-cluster combine (fixed order) + EMA + new_embed ----------
__global__ __launch_bounds__(256) void k_ema(const float* __restrict__ partial,
                                             const float* __restrict__ embed_avg,
                                             const int* __restrict__ substart,
                                             const float* __restrict__ cs,
                                             float* __restrict__ out_navg,
                                             float* __restrict__ out_nembed) {
    const int d = blockIdx.x;
    const int t = threadIdx.x;
#pragma unroll
    for (int i = 0; i < 4; i++) {
        int k = t + 256 * i;
        int s0 = substart[k], s1 = substart[k + 1];
        float s = 0.f;
        for (int sub = s0; sub < s1; sub++)
            s += partial[(size_t)sub * DIM + d];
        float navg = embed_avg[(size_t)d * NEMB + k] * (DECAY * DECAY) + (1.f - DECAY) * s;
        out_navg[(size_t)d * NEMB + k] = navg;
        out_nembed[(size_t)d * NEMB + k] = navg / cs[k];
    }
}

extern "C" void kernel_launch(void* const* d_in, const int* in_sizes, int n_in,
                              void* d_out, int out_size, void* d_ws, size_t ws_size,
                              hipStream_t stream) {
    const float* input        = (const float*)d_in[0];
    const float* embed        = (const float*)d_in[1];
    const float* cluster_size = (const float*)d_in[2];
    const float* embed_avg    = (const float*)d_in[3];

    float* out        = (float*)d_out;
    float* out_q      = out;                       // 16777216
    float* out_diff   = out + 16777216;            // 1
    float* out_ind    = out + 16777217;            // 65536
    float* out_ncs    = out + 16842753;            // 1024
    float* out_navg   = out + 16843777;            // 262144
    float* out_nembed = out + 17105921;            // 262144

    char* ws = (char*)d_ws;
    size_t o = 0;
    int*   w_ind      = (int*)(ws + o);   o += (size_t)NROWS * 4;
    float* w_embedT   = (float*)(ws + o); o += (size_t)DIM * NEMB * 4;
    float* w_enorm    = (float*)(ws + o); o += NEMB * 4;
    int*   w_counts   = (int*)(ws + o);   o += NEMB * 4;
    int*   w_offsets  = (int*)(ws + o);   o += NEMB * 4;
    int*   w_cursor   = (int*)(ws + o);   o += NEMB * 4;
    float* w_cs       = (float*)(ws + o); o += NEMB * 4;
    float* w_partials = (float*)(ws + o); o += 2048 * 4;
    int*   w_sorted   = (int*)(ws + o);   o += (size_t)NROWS * 4;
    int*   w_substart = (int*)(ws + o);   o += (NEMB + 4) * 4;
    float* w_partial  = (float*)(ws + o); o += (size_t)MAXSUB * DIM * 4;
    f16*   w_ehlT     = (f16*)(ws + o);   o += (size_t)NEMB * 512 * 2;

    k_enorm<<<16, 256, 0, stream>>>(embed, w_enorm, w_counts);
    k_prep<<<dim3(32, 8), dim3(32, 8), 0, stream>>>(embed, w_embedT, w_ehlT);
    k_argmin_mfma<<<NROWS / 128, 512, 0, stream>>>(input, w_ehlT, w_enorm, w_ind, out_ind);
    k_quant<<<2048, 256, 0, stream>>>(input, w_embedT, w_ind, out_q, w_partials);
    k_diff<<<1, 256, 0, stream>>>(w_partials, out_diff);
    k_hist<<<64, 256, 0, stream>>>(w_ind, w_counts);
    k_scan<<<1, 1024, 0, stream>>>(w_counts, cluster_size, w_offsets, w_cursor,
                                   w_substart, out_ncs, w_cs);
    k_scatter<<<NROWS / 256, 256, 0, stream>>>(w_ind, w_cursor, w_sorted);
    k_psum<<<MAXSUB, 256, 0, stream>>>(input, w_sorted, w_counts, w_offsets,
                                       w_substart, w_partial);
    k_ema<<<DIM, 256, 0, stream>>>(w_partial, embed_avg, w_substart, w_cs,
                                   out_navg, out_nembed);
}